// Round 1
// baseline (248.126 us; speedup 1.0000x reference)
//
#include <hip/hip_runtime.h>
#include <hip/hip_bf16.h>

typedef __hip_bfloat16 bf16;
typedef __attribute__((ext_vector_type(8))) short bf16x8;   // 8 bf16 = 4 VGPRs (MFMA A/B frag)
typedef __attribute__((ext_vector_type(4))) float f32x4;    // MFMA C/D frag

#define DEV static __device__ __forceinline__

DEV void gload_lds16(const void* g, void* l) {
  __builtin_amdgcn_global_load_lds((const __attribute__((address_space(1))) void*)g,
                                   (__attribute__((address_space(3))) void*)l, 16, 0, 0);
}

DEV f32x4 mfma16(bf16x8 a, bf16x8 b, f32x4 c) {
  return __builtin_amdgcn_mfma_f32_16x16x32_bf16(a, b, c, 0, 0, 0);
}

DEV unsigned short f2b_bits(float f) {  // RNE f32->bf16 (inputs are finite)
  unsigned int u = __float_as_uint(f);
  return (unsigned short)((u + 0x7fffu + ((u >> 16) & 1u)) >> 16);
}

// ---------------- small conversion / table kernels ----------------

__global__ void f2b4_kernel(const float4* __restrict__ src, ushort4* __restrict__ dst, int n4) {
  int i = blockIdx.x * 256 + threadIdx.x;
  if (i >= n4) return;
  float4 v = src[i];
  ushort4 o;
  o.x = f2b_bits(v.x); o.y = f2b_bits(v.y); o.z = f2b_bits(v.z); o.w = f2b_bits(v.w);
  dst[i] = o;
}

__global__ void rope_table_kernel(float2* __restrict__ tab) {
  int idx = blockIdx.x * 256 + threadIdx.x;   // s*32 + i
  if (idx >= 2048 * 32) return;
  int s = idx >> 5, i = idx & 31;
  // inv_freq = 10000^(-2i/64) = 2^(-2i/64 * log2(10000))
  float inv = exp2f(-(float)(2 * i) * (13.287712379549449f / 64.0f));
  float a = (float)s * inv;
  tab[idx] = make_float2(cosf(a), sinf(a));
}

// ---------------- GEMM: C[M][N] = A[M][K] * Bt[N][K]^T + bias ----------------
// 128x128 tile, BK=32, 4 waves (2x2), each wave 64x64 = 4x4 frags of 16x16x32.

template <typename OT>
__global__ __launch_bounds__(256)
void gemm_bt_kernel(const bf16* __restrict__ A, const bf16* __restrict__ Bt,
                    const float* __restrict__ bias, OT* __restrict__ C,
                    int M, int N, int K)
{
  __shared__ bf16 As[128 * 32];
  __shared__ bf16 Bs[128 * 32];
  const int t = threadIdx.x;
  const int lane = t & 63;
  const int wave = t >> 6;
  const int wm = (wave >> 1) * 64;
  const int wn = (wave & 1) * 64;
  const int bm = blockIdx.x * 128;
  const int bn = blockIdx.y * 128;

  // staging: thread t covers row t/4 (+64 on 2nd issue), 8 cols at (t%4)*8
  const int r4 = t >> 2;
  const int c8 = (t & 3) * 8;
  const bf16* Ag = A + (size_t)(bm + r4) * K + c8;
  const bf16* Bg = Bt + (size_t)(bn + r4) * K + c8;
  bf16* Asl = As + t * 8;
  bf16* Bsl = Bs + t * 8;

  f32x4 acc[4][4] = {};
  const int rr = lane & 15;
  const int kg = (lane >> 4) * 8;

  for (int k0 = 0; k0 < K; k0 += 32) {
    gload_lds16(Ag + k0, Asl);
    gload_lds16(Ag + (size_t)64 * K + k0, Asl + 2048);
    gload_lds16(Bg + k0, Bsl);
    gload_lds16(Bg + (size_t)64 * K + k0, Bsl + 2048);
    __syncthreads();
    bf16x8 af[4], bfr[4];
#pragma unroll
    for (int m = 0; m < 4; ++m) af[m] = *(const bf16x8*)&As[(wm + m * 16 + rr) * 32 + kg];
#pragma unroll
    for (int n = 0; n < 4; ++n) bfr[n] = *(const bf16x8*)&Bs[(wn + n * 16 + rr) * 32 + kg];
#pragma unroll
    for (int m = 0; m < 4; ++m)
#pragma unroll
      for (int n = 0; n < 4; ++n)
        acc[m][n] = mfma16(af[m], bfr[n], acc[m][n]);
    __syncthreads();
  }

  const int rg = (lane >> 4) * 4;
#pragma unroll
  for (int n = 0; n < 4; ++n) {
    const int col = bn + wn + n * 16 + rr;
    const float bv = bias[col];
#pragma unroll
    for (int m = 0; m < 4; ++m) {
#pragma unroll
      for (int r = 0; r < 4; ++r) {
        const int row = bm + wm + m * 16 + rg + r;
        float v = acc[m][n][r] + bv;
        if constexpr (sizeof(OT) == 2) C[(size_t)row * N + col] = __float2bfloat16(v);
        else                           C[(size_t)row * N + col] = v;
      }
    }
  }
}

// ---------------- RoPE + reshape ----------------
// QKV[row][f], f = qkv*512 + d*8 + h.  Emits roped Q,K as [bvh][s][64],
// V transposed as VT[bvh][d][s] (so PV B-frags are contiguous bf16x8 loads).

__global__ void rope_reshape_kernel(const bf16* __restrict__ QKV, const float2* __restrict__ tab,
                                    bf16* __restrict__ Q, bf16* __restrict__ K, bf16* __restrict__ VT)
{
  int idx = blockIdx.x * 256 + threadIdx.x;   // [0, 32*2048*32)
  int i = idx & 31;            // d-pair index
  int s = (idx >> 5) & 2047;
  int bvh = idx >> 16;
  int bv = bvh >> 3, h = bvh & 7;
  const bf16* row = QKV + (size_t)(bv * 2048 + s) * 1536;
  float2 cs = tab[(s << 5) + i];
  float q0 = __bfloat162float(row[(2 * i) * 8 + h]);
  float q1 = __bfloat162float(row[(2 * i + 1) * 8 + h]);
  float k0 = __bfloat162float(row[512 + (2 * i) * 8 + h]);
  float k1 = __bfloat162float(row[512 + (2 * i + 1) * 8 + h]);
  size_t qb = (size_t)bvh * (2048 * 64) + (size_t)s * 64 + 2 * i;
  Q[qb]     = __float2bfloat16(q0 * cs.x - q1 * cs.y);
  Q[qb + 1] = __float2bfloat16(q1 * cs.x + q0 * cs.y);
  K[qb]     = __float2bfloat16(k0 * cs.x - k1 * cs.y);
  K[qb + 1] = __float2bfloat16(k1 * cs.x + k0 * cs.y);
  size_t vb = (size_t)bvh * (2048 * 64);
  VT[vb + (size_t)(2 * i) * 2048 + s]     = row[1024 + (2 * i) * 8 + h];
  VT[vb + (size_t)(2 * i + 1) * 2048 + s] = row[1024 + (2 * i + 1) * 8 + h];
}

// ---------------- causal flash attention ----------------
// block = (bvh, 128 q-rows); 4 waves x 32 rows; K-blocks of 64.
// K/VT tiles LDS-staged with chunk-XOR swizzle (conflict-free ds_read_b128).
// Online softmax in f32; P goes C-layout -> (wave-local LDS) -> A-layout.

__global__ __launch_bounds__(256)
void attn_kernel(const bf16* __restrict__ Q, const bf16* __restrict__ K,
                 const bf16* __restrict__ VT, bf16* __restrict__ O)
{
  __shared__ bf16 Kt[64 * 64];
  __shared__ bf16 Vt[64 * 64];
  __shared__ bf16 Pt[4][32 * 64];

  const int t = threadIdx.x;
  const int lane = t & 63;
  const int wq = t >> 6;
  const int qtb = blockIdx.x * 128;
  const int bvh = blockIdx.y;
  const int bv = bvh >> 3, h = bvh & 7;
  const size_t base = (size_t)bvh * (2048 * 64);

  const int rr = lane & 15;
  const int kg = lane >> 4;      // 0..3
  const int l7 = lane & 7;

  // Q fragments live in registers for the whole K-loop
  bf16x8 qf[2][2];
#pragma unroll
  for (int m = 0; m < 2; ++m)
#pragma unroll
    for (int kk = 0; kk < 2; ++kk)
      qf[m][kk] = *(const bf16x8*)&Q[base + (size_t)(qtb + wq * 32 + m * 16 + rr) * 64 + kg * 8 + kk * 32];

  f32x4 Oa[2][4] = {};
  float Mx[2][4], Ls[2][4];
#pragma unroll
  for (int m = 0; m < 2; ++m)
#pragma unroll
    for (int r = 0; r < 4; ++r) { Mx[m][r] = -INFINITY; Ls[m][r] = 0.0f; }

  const int nkb = qtb / 64 + 2;   // causal: only tiles up to the diagonal
  const int sr = t >> 3;          // staging row 0..31
  const int sc = t & 7;           // staging 16B-chunk 0..7

  for (int kb = 0; kb < nkb; ++kb) {
#pragma unroll
    for (int i = 0; i < 2; ++i) {
      int r = i * 32 + sr;
      int gc = (sc ^ (r & 7)) * 8;   // pre-swizzled global source (linear LDS dest)
      gload_lds16(&K[base + (size_t)(kb * 64 + r) * 64 + gc], &Kt[i * 2048 + t * 8]);
      gload_lds16(&VT[base + (size_t)r * 2048 + kb * 64 + gc], &Vt[i * 2048 + t * 8]);
    }
    __syncthreads();

    // S = Q K^T
    f32x4 S[2][4] = {};
#pragma unroll
    for (int f = 0; f < 4; ++f) {
#pragma unroll
      for (int kk = 0; kk < 2; ++kk) {
        bf16x8 kf = *(const bf16x8*)&Kt[(f * 16 + rr) * 64 + (((kg + kk * 4) ^ l7) * 8)];
#pragma unroll
        for (int m = 0; m < 2; ++m)
          S[m][f] = mfma16(qf[m][kk], kf, S[m][f]);
      }
    }

    // online softmax (rows live in 16-lane groups; 4 rows/lane via regs)
#pragma unroll
    for (int m = 0; m < 2; ++m) {
#pragma unroll
      for (int r = 0; r < 4; ++r) {
        const int qrow = qtb + wq * 32 + m * 16 + kg * 4 + r;
        float mx = -INFINITY;
#pragma unroll
        for (int f = 0; f < 4; ++f) {
          int col = kb * 64 + f * 16 + rr;
          float sv = S[m][f][r] * 0.125f;
          sv = (col <= qrow) ? sv : -INFINITY;
          S[m][f][r] = sv;
          mx = fmaxf(mx, sv);
        }
#pragma unroll
        for (int d = 1; d < 16; d <<= 1) mx = fmaxf(mx, __shfl_xor(mx, d, 64));
        const float newM = fmaxf(Mx[m][r], mx);
        const float alpha = __expf(Mx[m][r] - newM);  // -inf only on 1st block -> 0
        float rs = 0.0f;
#pragma unroll
        for (int f = 0; f < 4; ++f) {
          float pv = __expf(S[m][f][r] - newM);
          S[m][f][r] = pv;
          rs += pv;
        }
#pragma unroll
        for (int d = 1; d < 16; d <<= 1) rs += __shfl_xor(rs, d, 64);
        Ls[m][r] = Ls[m][r] * alpha + rs;
        Mx[m][r] = newM;
#pragma unroll
        for (int df = 0; df < 4; ++df) Oa[m][df][r] *= alpha;
      }
      // C-layout -> wave-local LDS (bf16, chunk-XOR swizzled)
#pragma unroll
      for (int r = 0; r < 4; ++r) {
        const int prow = m * 16 + kg * 4 + r;
#pragma unroll
        for (int f = 0; f < 4; ++f) {
          int cb = (f * 2 + (rr >> 3)) ^ (prow & 7);
          Pt[wq][prow * 64 + cb * 8 + (rr & 7)] = __float2bfloat16(S[m][f][r]);
        }
      }
    }

    // O += P V   (A-frags of P from wave-local LDS; B-frags from VT tile)
#pragma unroll
    for (int kk2 = 0; kk2 < 2; ++kk2) {
      bf16x8 pf[2];
#pragma unroll
      for (int m = 0; m < 2; ++m)
        pf[m] = *(const bf16x8*)&Pt[wq][(m * 16 + rr) * 64 + (((kg + kk2 * 4) ^ l7) * 8)];
#pragma unroll
      for (int df = 0; df < 4; ++df) {
        bf16x8 vf = *(const bf16x8*)&Vt[(df * 16 + rr) * 64 + (((kg + kk2 * 4) ^ l7) * 8)];
#pragma unroll
        for (int m = 0; m < 2; ++m)
          Oa[m][df] = mfma16(pf[m], vf, Oa[m][df]);
      }
    }
    __syncthreads();   // protect Kt/Vt before next staging
  }

  // normalize + write O as [bv][s][h*64+d]
#pragma unroll
  for (int m = 0; m < 2; ++m)
#pragma unroll
    for (int r = 0; r < 4; ++r) {
      const int qrow = qtb + wq * 32 + m * 16 + kg * 4 + r;
      const float inv = 1.0f / Ls[m][r];
      size_t ob = ((size_t)bv * 2048 + qrow) * 512 + h * 64;
#pragma unroll
      for (int df = 0; df < 4; ++df)
        O[ob + df * 16 + rr] = __float2bfloat16(Oa[m][df][r] * inv);
    }
}

// ---------------- launch ----------------

extern "C" void kernel_launch(void* const* d_in, const int* in_sizes, int n_in,
                              void* d_out, int out_size, void* d_ws, size_t ws_size,
                              hipStream_t stream)
{
  const float* x    = (const float*)d_in[1];
  const float* wqkv = (const float*)d_in[2];
  const float* bqkv = (const float*)d_in[3];
  const float* wo   = (const float*)d_in[4];
  const float* bo   = (const float*)d_in[5];
  float* out = (float*)d_out;

  char* p = (char*)d_ws;
  bf16* Xb   = (bf16*)p; p += (size_t)8192 * 512 * 2;      // 8 MB
  bf16* Wqb  = (bf16*)p; p += (size_t)1536 * 512 * 2;      // 1.5 MB
  bf16* Wob  = (bf16*)p; p += (size_t)512 * 512 * 2;       // 0.5 MB
  bf16* QKVb = (bf16*)p; p += (size_t)8192 * 1536 * 2;     // 24 MB
  bf16* Qr   = (bf16*)p; p += (size_t)32 * 2048 * 64 * 2;  // 8 MB
  bf16* Kr   = (bf16*)p; p += (size_t)32 * 2048 * 64 * 2;  // 8 MB
  bf16* VTr  = (bf16*)p; p += (size_t)32 * 2048 * 64 * 2;  // 8 MB
  bf16* Ob   = (bf16*)p; p += (size_t)8192 * 512 * 2;      // 8 MB
  float2* tab = (float2*)p; p += (size_t)2048 * 32 * 8;    // 0.5 MB   (total ~66.5 MB)

  f2b4_kernel<<<4096, 256, 0, stream>>>((const float4*)x,    (ushort4*)Xb,  8192 * 512 / 4);
  f2b4_kernel<<<768,  256, 0, stream>>>((const float4*)wqkv, (ushort4*)Wqb, 1536 * 512 / 4);
  f2b4_kernel<<<256,  256, 0, stream>>>((const float4*)wo,   (ushort4*)Wob, 512 * 512 / 4);
  rope_table_kernel<<<256, 256, 0, stream>>>(tab);

  gemm_bt_kernel<bf16><<<dim3(64, 12), 256, 0, stream>>>(Xb, Wqb, bqkv, QKVb, 8192, 1536, 512);
  rope_reshape_kernel<<<8192, 256, 0, stream>>>(QKVb, tab, Qr, Kr, VTr);
  attn_kernel<<<dim3(16, 32), 256, 0, stream>>>(Qr, Kr, VTr, Ob);
  gemm_bt_kernel<float><<<dim3(64, 4), 256, 0, stream>>>(Ob, Wob, bo, out, 8192, 512, 512);
}

// Round 2
// 166.358 us; speedup vs baseline: 1.4915x; 1.4915x over previous
//
#include <hip/hip_runtime.h>
#include <hip/hip_bf16.h>

typedef __hip_bfloat16 bf16;
typedef __attribute__((ext_vector_type(8))) short bf16x8;   // 8 bf16 = 4 VGPRs (MFMA A/B frag)
typedef __attribute__((ext_vector_type(4))) float f32x4;    // MFMA C/D frag

#define DEV static __device__ __forceinline__

DEV void gload_lds16(const void* g, void* l) {
  __builtin_amdgcn_global_load_lds((const __attribute__((address_space(1))) void*)g,
                                   (__attribute__((address_space(3))) void*)l, 16, 0, 0);
}

DEV f32x4 mfma16(bf16x8 a, bf16x8 b, f32x4 c) {
  return __builtin_amdgcn_mfma_f32_16x16x32_bf16(a, b, c, 0, 0, 0);
}

DEV unsigned short f2b_bits(float f) {  // RNE f32->bf16 (inputs are finite)
  unsigned int u = __float_as_uint(f);
  return (unsigned short)((u + 0x7fffu + ((u >> 16) & 1u)) >> 16);
}

// ---------------- small conversion / table kernels ----------------

__global__ void f2b4_kernel(const float4* __restrict__ src, ushort4* __restrict__ dst, int n4) {
  int i = blockIdx.x * 256 + threadIdx.x;
  if (i >= n4) return;
  float4 v = src[i];
  ushort4 o;
  o.x = f2b_bits(v.x); o.y = f2b_bits(v.y); o.z = f2b_bits(v.z); o.w = f2b_bits(v.w);
  dst[i] = o;
}

__global__ void rope_table_kernel(float2* __restrict__ tab) {
  int idx = blockIdx.x * 256 + threadIdx.x;   // s*32 + i
  if (idx >= 2048 * 32) return;
  int s = idx >> 5, i = idx & 31;
  float inv = exp2f(-(float)(2 * i) * (13.287712379549449f / 64.0f));
  float a = (float)s * inv;
  tab[idx] = make_float2(cosf(a), sinf(a));
}

// ---------------- GEMM: C[M][N] = A[M][K] * Bt[N][K]^T + bias ----------------

template <typename OT>
__global__ __launch_bounds__(256)
void gemm_bt_kernel(const bf16* __restrict__ A, const bf16* __restrict__ Bt,
                    const float* __restrict__ bias, OT* __restrict__ C,
                    int M, int N, int K)
{
  __shared__ bf16 As[128 * 32];
  __shared__ bf16 Bs[128 * 32];
  const int t = threadIdx.x;
  const int lane = t & 63;
  const int wave = t >> 6;
  const int wm = (wave >> 1) * 64;
  const int wn = (wave & 1) * 64;
  const int bm = blockIdx.x * 128;
  const int bn = blockIdx.y * 128;

  const int r4 = t >> 2;
  const int c8 = (t & 3) * 8;
  const bf16* Ag = A + (size_t)(bm + r4) * K + c8;
  const bf16* Bg = Bt + (size_t)(bn + r4) * K + c8;
  bf16* Asl = As + t * 8;
  bf16* Bsl = Bs + t * 8;

  f32x4 acc[4][4] = {};
  const int rr = lane & 15;
  const int kg = (lane >> 4) * 8;

  for (int k0 = 0; k0 < K; k0 += 32) {
    gload_lds16(Ag + k0, Asl);
    gload_lds16(Ag + (size_t)64 * K + k0, Asl + 2048);
    gload_lds16(Bg + k0, Bsl);
    gload_lds16(Bg + (size_t)64 * K + k0, Bsl + 2048);
    __syncthreads();
    bf16x8 af[4], bfr[4];
#pragma unroll
    for (int m = 0; m < 4; ++m) af[m] = *(const bf16x8*)&As[(wm + m * 16 + rr) * 32 + kg];
#pragma unroll
    for (int n = 0; n < 4; ++n) bfr[n] = *(const bf16x8*)&Bs[(wn + n * 16 + rr) * 32 + kg];
#pragma unroll
    for (int m = 0; m < 4; ++m)
#pragma unroll
      for (int n = 0; n < 4; ++n)
        acc[m][n] = mfma16(af[m], bfr[n], acc[m][n]);
    __syncthreads();
  }

  const int rg = (lane >> 4) * 4;
#pragma unroll
  for (int n = 0; n < 4; ++n) {
    const int col = bn + wn + n * 16 + rr;
    const float bv = bias[col];
#pragma unroll
    for (int m = 0; m < 4; ++m) {
#pragma unroll
      for (int r = 0; r < 4; ++r) {
        const int row = bm + wm + m * 16 + rg + r;
        float v = acc[m][n][r] + bv;
        if constexpr (sizeof(OT) == 2) C[(size_t)row * N + col] = __float2bfloat16(v);
        else                           C[(size_t)row * N + col] = v;
      }
    }
  }
}

// ---------------- RoPE + reshape ----------------
// QKV[row][f], f = qkv*512 + d*8 + h.  Emits roped Q (pre-scaled by 1/8), K as
// [bvh][s][64], V transposed as VT[bvh][d][s].

__global__ void rope_reshape_kernel(const bf16* __restrict__ QKV, const float2* __restrict__ tab,
                                    bf16* __restrict__ Q, bf16* __restrict__ K, bf16* __restrict__ VT)
{
  int idx = blockIdx.x * 256 + threadIdx.x;   // [0, 32*2048*32)
  int i = idx & 31;            // d-pair index
  int s = (idx >> 5) & 2047;
  int bvh = idx >> 16;
  int bv = bvh >> 3, h = bvh & 7;
  const bf16* row = QKV + (size_t)(bv * 2048 + s) * 1536;
  float2 cs = tab[(s << 5) + i];
  float q0 = __bfloat162float(row[(2 * i) * 8 + h]);
  float q1 = __bfloat162float(row[(2 * i + 1) * 8 + h]);
  float k0 = __bfloat162float(row[512 + (2 * i) * 8 + h]);
  float k1 = __bfloat162float(row[512 + (2 * i + 1) * 8 + h]);
  size_t qb = (size_t)bvh * (2048 * 64) + (size_t)s * 64 + 2 * i;
  Q[qb]     = __float2bfloat16((q0 * cs.x - q1 * cs.y) * 0.125f);   // fold softmax scale
  Q[qb + 1] = __float2bfloat16((q1 * cs.x + q0 * cs.y) * 0.125f);
  K[qb]     = __float2bfloat16(k0 * cs.x - k1 * cs.y);
  K[qb + 1] = __float2bfloat16(k1 * cs.x + k0 * cs.y);
  size_t vb = (size_t)bvh * (2048 * 64);
  VT[vb + (size_t)(2 * i) * 2048 + s]     = row[1024 + (2 * i) * 8 + h];
  VT[vb + (size_t)(2 * i + 1) * 2048 + s] = row[1024 + (2 * i + 1) * 8 + h];
}

// ---------------- causal flash attention ----------------
// block = (bvh, 128 q-rows); 8 waves x 16 rows; K-blocks of 64, double-buffered
// LDS, one barrier/iter. Deferred row-sum (per-lane partials, reduced once at
// end). Masking/compute skipped where wave-uniformly possible.

__global__ __launch_bounds__(512, 4)
void attn_kernel(const bf16* __restrict__ Q, const bf16* __restrict__ K,
                 const bf16* __restrict__ VT, bf16* __restrict__ O)
{
  __shared__ bf16 Kt[2][64 * 64];
  __shared__ bf16 Vt[2][64 * 64];
  __shared__ bf16 Pt[8][16 * 64];

  const int t = threadIdx.x;
  const int lane = t & 63;
  const int w = t >> 6;
  const int qtb = blockIdx.x * 128;
  const int bvh = blockIdx.y;
  const int bv = bvh >> 3, h = bvh & 7;
  const size_t base = (size_t)bvh * (2048 * 64);

  const int rr = lane & 15;
  const int kg = lane >> 4;      // 0..3
  const int s7 = rr & 7;
  const int q0 = qtb + w * 16;   // wave's first q-row

  // Q fragments (rows q0..q0+15) in registers for the whole K-loop
  bf16x8 qf[2];
#pragma unroll
  for (int kk = 0; kk < 2; ++kk)
    qf[kk] = *(const bf16x8*)&Q[base + (size_t)(q0 + rr) * 64 + kk * 32 + kg * 8];

  f32x4 Oa[4] = {};
  float Mx[4], Ls[4];
#pragma unroll
  for (int r = 0; r < 4; ++r) { Mx[r] = -INFINITY; Ls[r] = 0.0f; }

  const int nkb = 2 * blockIdx.x + 2;   // causal: K-blocks up to the diagonal
  const int sr = t >> 3;                // staging row 0..63
  const int sc = t & 7;                 // staging 16B-chunk 0..7
  const int gc = (sc ^ (sr & 7)) * 8;   // pre-swizzled global col (linear LDS dest)

  auto stage = [&](int buf, int kb) {
    gload_lds16(&K[base + (size_t)(kb * 64 + sr) * 64 + gc], &Kt[buf][t * 8]);
    gload_lds16(&VT[base + (size_t)sr * 2048 + kb * 64 + gc], &Vt[buf][t * 8]);
  };

  stage(0, 0);
  int cur = 0;

  for (int kb = 0; kb < nkb; ++kb) {
    __syncthreads();                       // drains vmcnt(0): buf[cur] ready
    if (kb + 1 < nkb) stage(cur ^ 1, kb + 1);   // overlaps with compute below

    if (kb * 64 <= q0 + 15) {              // skip fully-masked K-blocks
      // S = Q K^T
      f32x4 S[4] = {};
#pragma unroll
      for (int f = 0; f < 4; ++f) {
#pragma unroll
        for (int kk = 0; kk < 2; ++kk) {
          bf16x8 kf = *(const bf16x8*)&Kt[cur][(f * 16 + rr) * 64 + (((kk * 4 + kg) ^ s7) * 8)];
          S[f] = mfma16(qf[kk], kf, S[f]);
        }
      }

      const bool dg = (kb * 64 + 63 > q0);  // diagonal block -> needs masking
#pragma unroll
      for (int r = 0; r < 4; ++r) {
        const int qrow = q0 + kg * 4 + r;
        if (dg) {
#pragma unroll
          for (int f = 0; f < 4; ++f)
            S[f][r] = (kb * 64 + f * 16 + rr <= qrow) ? S[f][r] : -INFINITY;
        }
        float mx = fmaxf(fmaxf(S[0][r], S[1][r]), fmaxf(S[2][r], S[3][r]));
#pragma unroll
        for (int d = 1; d < 16; d <<= 1) mx = fmaxf(mx, __shfl_xor(mx, d, 64));
        const float newM = fmaxf(Mx[r], mx);
        const float alpha = __expf(Mx[r] - newM);
        float rs = 0.0f;
#pragma unroll
        for (int f = 0; f < 4; ++f) {
          float pv = __expf(S[f][r] - newM);
          S[f][r] = pv;
          rs += pv;
        }
        Ls[r] = Ls[r] * alpha + rs;        // per-lane partial; reduced at end
        Mx[r] = newM;
#pragma unroll
        for (int df = 0; df < 4; ++df) Oa[df][r] *= alpha;
        // C-layout -> wave-local LDS (bf16, chunk-XOR swizzled)
        const int prow = kg * 4 + r;
#pragma unroll
        for (int f = 0; f < 4; ++f) {
          int cb = (f * 2 + (rr >> 3)) ^ (prow & 7);
          Pt[w][prow * 64 + cb * 8 + (rr & 7)] = __float2bfloat16(S[f][r]);
        }
      }

      // O += P V
#pragma unroll
      for (int kk2 = 0; kk2 < 2; ++kk2) {
        bf16x8 pf = *(const bf16x8*)&Pt[w][rr * 64 + (((kk2 * 4 + kg) ^ s7) * 8)];
#pragma unroll
        for (int df = 0; df < 4; ++df) {
          bf16x8 vf = *(const bf16x8*)&Vt[cur][(df * 16 + rr) * 64 + (((kk2 * 4 + kg) ^ s7) * 8)];
          Oa[df] = mfma16(pf, vf, Oa[df]);
        }
      }
    }
    cur ^= 1;
  }

  // final row-sum reduction (once), normalize, write O as [bv][s][h*64+d]
#pragma unroll
  for (int r = 0; r < 4; ++r) {
#pragma unroll
    for (int d = 1; d < 16; d <<= 1) Ls[r] += __shfl_xor(Ls[r], d, 64);
    const int qrow = q0 + kg * 4 + r;
    const float inv = 1.0f / Ls[r];
    size_t ob = ((size_t)bv * 2048 + qrow) * 512 + h * 64;
#pragma unroll
    for (int df = 0; df < 4; ++df)
      O[ob + df * 16 + rr] = __float2bfloat16(Oa[df][r] * inv);
  }
}

// ---------------- launch ----------------

extern "C" void kernel_launch(void* const* d_in, const int* in_sizes, int n_in,
                              void* d_out, int out_size, void* d_ws, size_t ws_size,
                              hipStream_t stream)
{
  const float* x    = (const float*)d_in[1];
  const float* wqkv = (const float*)d_in[2];
  const float* bqkv = (const float*)d_in[3];
  const float* wo   = (const float*)d_in[4];
  const float* bo   = (const float*)d_in[5];
  float* out = (float*)d_out;

  char* p = (char*)d_ws;
  bf16* Xb   = (bf16*)p; p += (size_t)8192 * 512 * 2;
  bf16* Wqb  = (bf16*)p; p += (size_t)1536 * 512 * 2;
  bf16* Wob  = (bf16*)p; p += (size_t)512 * 512 * 2;
  bf16* QKVb = (bf16*)p; p += (size_t)8192 * 1536 * 2;
  bf16* Qr   = (bf16*)p; p += (size_t)32 * 2048 * 64 * 2;
  bf16* Kr   = (bf16*)p; p += (size_t)32 * 2048 * 64 * 2;
  bf16* VTr  = (bf16*)p; p += (size_t)32 * 2048 * 64 * 2;
  bf16* Ob   = (bf16*)p; p += (size_t)8192 * 512 * 2;
  float2* tab = (float2*)p; p += (size_t)2048 * 32 * 8;

  f2b4_kernel<<<4096, 256, 0, stream>>>((const float4*)x,    (ushort4*)Xb,  8192 * 512 / 4);
  f2b4_kernel<<<768,  256, 0, stream>>>((const float4*)wqkv, (ushort4*)Wqb, 1536 * 512 / 4);
  f2b4_kernel<<<256,  256, 0, stream>>>((const float4*)wo,   (ushort4*)Wob, 512 * 512 / 4);
  rope_table_kernel<<<256, 256, 0, stream>>>(tab);

  gemm_bt_kernel<bf16><<<dim3(64, 12), 256, 0, stream>>>(Xb, Wqb, bqkv, QKVb, 8192, 1536, 512);
  rope_reshape_kernel<<<8192, 256, 0, stream>>>(QKVb, tab, Qr, Kr, VTr);
  attn_kernel<<<dim3(16, 32), 512, 0, stream>>>(Qr, Kr, VTr, Ob);
  gemm_bt_kernel<float><<<dim3(64, 4), 256, 0, stream>>>(Ob, Wob, bo, out, 8192, 512, 512);
}

// Round 3
// 124.731 us; speedup vs baseline: 1.9893x; 1.3337x over previous
//
#include <hip/hip_runtime.h>
#include <hip/hip_bf16.h>

typedef __hip_bfloat16 bf16;
typedef __attribute__((ext_vector_type(8))) short bf16x8;   // 8 bf16 = 4 VGPRs (MFMA A/B frag)
typedef __attribute__((ext_vector_type(4))) float f32x4;    // MFMA C/D frag

#define DEV static __device__ __forceinline__

DEV void gload_lds16(const void* g, void* l) {
  __builtin_amdgcn_global_load_lds((const __attribute__((address_space(1))) void*)g,
                                   (__attribute__((address_space(3))) void*)l, 16, 0, 0);
}

DEV f32x4 mfma16(bf16x8 a, bf16x8 b, f32x4 c) {
  return __builtin_amdgcn_mfma_f32_16x16x32_bf16(a, b, c, 0, 0, 0);
}

DEV unsigned short f2b_bits(float f) {  // RNE f32->bf16 (inputs are finite)
  unsigned int u = __float_as_uint(f);
  return (unsigned short)((u + 0x7fffu + ((u >> 16) & 1u)) >> 16);
}

// ---------------- small conversion / table kernels ----------------

__global__ void f2b4_kernel(const float4* __restrict__ src, ushort4* __restrict__ dst, int n4) {
  int i = blockIdx.x * 256 + threadIdx.x;
  if (i >= n4) return;
  float4 v = src[i];
  ushort4 o;
  o.x = f2b_bits(v.x); o.y = f2b_bits(v.y); o.z = f2b_bits(v.z); o.w = f2b_bits(v.w);
  dst[i] = o;
}

__global__ void rope_table_kernel(float2* __restrict__ tab) {
  int idx = blockIdx.x * 256 + threadIdx.x;   // s*32 + i
  if (idx >= 2048 * 32) return;
  int s = idx >> 5, i = idx & 31;
  float inv = exp2f(-(float)(2 * i) * (13.287712379549449f / 64.0f));
  float a = (float)s * inv;
  tab[idx] = make_float2(cosf(a), sinf(a));
}

// ---------------- GEMM: C[M][N] = A[M][K] * Bt[N][K]^T + bias ----------------

template <typename OT>
__global__ __launch_bounds__(256)
void gemm_bt_kernel(const bf16* __restrict__ A, const bf16* __restrict__ Bt,
                    const float* __restrict__ bias, OT* __restrict__ C,
                    int M, int N, int K)
{
  __shared__ bf16 As[128 * 32];
  __shared__ bf16 Bs[128 * 32];
  const int t = threadIdx.x;
  const int lane = t & 63;
  const int wave = t >> 6;
  const int wm = (wave >> 1) * 64;
  const int wn = (wave & 1) * 64;
  const int bm = blockIdx.x * 128;
  const int bn = blockIdx.y * 128;

  const int r4 = t >> 2;
  const int c8 = (t & 3) * 8;
  const bf16* Ag = A + (size_t)(bm + r4) * K + c8;
  const bf16* Bg = Bt + (size_t)(bn + r4) * K + c8;
  bf16* Asl = As + t * 8;
  bf16* Bsl = Bs + t * 8;

  f32x4 acc[4][4] = {};
  const int rr = lane & 15;
  const int kg = (lane >> 4) * 8;

  for (int k0 = 0; k0 < K; k0 += 32) {
    gload_lds16(Ag + k0, Asl);
    gload_lds16(Ag + (size_t)64 * K + k0, Asl + 2048);
    gload_lds16(Bg + k0, Bsl);
    gload_lds16(Bg + (size_t)64 * K + k0, Bsl + 2048);
    __syncthreads();
    bf16x8 af[4], bfr[4];
#pragma unroll
    for (int m = 0; m < 4; ++m) af[m] = *(const bf16x8*)&As[(wm + m * 16 + rr) * 32 + kg];
#pragma unroll
    for (int n = 0; n < 4; ++n) bfr[n] = *(const bf16x8*)&Bs[(wn + n * 16 + rr) * 32 + kg];
#pragma unroll
    for (int m = 0; m < 4; ++m)
#pragma unroll
      for (int n = 0; n < 4; ++n)
        acc[m][n] = mfma16(af[m], bfr[n], acc[m][n]);
    __syncthreads();
  }

  const int rg = (lane >> 4) * 4;
#pragma unroll
  for (int n = 0; n < 4; ++n) {
    const int col = bn + wn + n * 16 + rr;
    const float bv = bias[col];
#pragma unroll
    for (int m = 0; m < 4; ++m) {
#pragma unroll
      for (int r = 0; r < 4; ++r) {
        const int row = bm + wm + m * 16 + rg + r;
        float v = acc[m][n][r] + bv;
        if constexpr (sizeof(OT) == 2) C[(size_t)row * N + col] = __float2bfloat16(v);
        else                           C[(size_t)row * N + col] = v;
      }
    }
  }
}

// ---------------- RoPE + reshape (Q, K only) ----------------
// QKV[row][f], f = qkv*512 + d*8 + h.  Emits roped Q (pre-scaled by 1/8), K as
// [bvh][s][64].

__global__ void rope_reshape_kernel(const bf16* __restrict__ QKV, const float2* __restrict__ tab,
                                    bf16* __restrict__ Q, bf16* __restrict__ K)
{
  int idx = blockIdx.x * 256 + threadIdx.x;   // [0, 32*2048*32)
  int i = idx & 31;            // d-pair index
  int s = (idx >> 5) & 2047;
  int bvh = idx >> 16;
  int bv = bvh >> 3, h = bvh & 7;
  const bf16* row = QKV + (size_t)(bv * 2048 + s) * 1536;
  float2 cs = tab[(s << 5) + i];
  float q0 = __bfloat162float(row[(2 * i) * 8 + h]);
  float q1 = __bfloat162float(row[(2 * i + 1) * 8 + h]);
  float k0 = __bfloat162float(row[512 + (2 * i) * 8 + h]);
  float k1 = __bfloat162float(row[512 + (2 * i + 1) * 8 + h]);
  size_t qb = (size_t)bvh * (2048 * 64) + (size_t)s * 64 + 2 * i;
  Q[qb]     = __float2bfloat16((q0 * cs.x - q1 * cs.y) * 0.125f);   // fold softmax scale
  Q[qb + 1] = __float2bfloat16((q1 * cs.x + q0 * cs.y) * 0.125f);
  K[qb]     = __float2bfloat16(k0 * cs.x - k1 * cs.y);
  K[qb + 1] = __float2bfloat16(k1 * cs.x + k0 * cs.y);
}

// ---------------- V transpose: QKV -> VT[bvh][d][s] ----------------
// LDS-tiled so VT writes are coalesced 32B runs.

__global__ __launch_bounds__(256)
void vtrans_kernel(const bf16* __restrict__ QKV, bf16* __restrict__ VT)
{
  __shared__ unsigned short L[64][66];   // pad 66 -> 2-way max on writes
  const int stile = blockIdx.x;          // 0..31 (x => h-siblings share XCD/L2)
  const int bvh = blockIdx.y;            // 0..31
  const int bv = bvh >> 3, h = bvh & 7;
  const int t = threadIdx.x;
  const int s0 = stile * 64;

  // phase 1: gather V[s][d] for this (bvh, stile) into LDS
  const int sl = t >> 2;                 // 0..63
  const int dg = (t & 3) * 16;
  const unsigned short* src =
      (const unsigned short*)(QKV + (size_t)(bv * 2048 + s0 + sl) * 1536 + 1024 + h);
#pragma unroll
  for (int j = 0; j < 16; ++j)
    L[sl][dg + j] = src[(size_t)(dg + j) * 8];
  __syncthreads();

  // phase 2: write VT[d][s] coalesced (each thread: 16 consecutive s)
  const int d = t >> 2;
  const int sb = (t & 3) * 16;
  unsigned short* dst = (unsigned short*)(VT + (size_t)bvh * (64 * 2048) + (size_t)d * 2048 + s0 + sb);
#pragma unroll
  for (int q = 0; q < 4; ++q) {
    ushort4 o;
    o.x = L[sb + q * 4 + 0][d];
    o.y = L[sb + q * 4 + 1][d];
    o.z = L[sb + q * 4 + 2][d];
    o.w = L[sb + q * 4 + 3][d];
    *(ushort4*)(dst + q * 4) = o;
  }
}

// ---------------- causal flash attention ----------------
// Balanced tile-pairs: block = (bvh, pair p) handles q-tiles t=p and t=31-p
// (64 rows each, sequentially) => every block runs exactly 17 K-iterations.
// KVBLK=128, double-buffered LDS (1 barrier/iter), 4 waves x 16 q-rows.
// Defer-max online softmax (THR=8): common path has no cross-lane ops and no
// O-rescale; row-sum reduced once at the end.

__global__ __launch_bounds__(256, 2)
void attn_kernel(const bf16* __restrict__ Q, const bf16* __restrict__ K,
                 const bf16* __restrict__ VT, bf16* __restrict__ O)
{
  __shared__ bf16 Kt[2][128 * 64];   // [k-row][d]
  __shared__ bf16 Vt[2][64 * 128];   // [d][k-col]
  __shared__ bf16 Pt[4][16 * 128];   // per-wave P tile

  const int t = threadIdx.x;
  const int lane = t & 63;
  const int w = t >> 6;              // wave 0..3
  const int bvh = blockIdx.x;        // 0..31  (linear%8 = bvh%8 -> L2 locality)
  const int pair = blockIdx.y;       // 0..15
  const int bv = bvh >> 3, h = bvh & 7;
  const size_t base = (size_t)bvh * (2048 * 64);

  const int rr = lane & 15;
  const int kg = lane >> 4;          // 0..3
  const int s7 = rr & 7;

  auto stage = [&](int buf, int kb) {
#pragma unroll
    for (int i = 0; i < 4; ++i) {     // K tile: 128 rows x 8 chunks
      int c = i * 256 + t;
      int r = c >> 3, sc = c & 7;
      gload_lds16(&K[base + (size_t)(kb * 128 + r) * 64 + ((sc ^ (r & 7)) * 8)],
                  &Kt[buf][c * 8]);
    }
#pragma unroll
    for (int i = 0; i < 4; ++i) {     // V tile: 64 rows x 16 chunks
      int c = i * 256 + t;
      int d = c >> 4, sc = c & 15;
      gload_lds16(&VT[base + (size_t)d * 2048 + kb * 128 + ((sc ^ (d & 7)) * 8)],
                  &Vt[buf][c * 8]);
    }
  };

#pragma unroll 1
  for (int pass = 0; pass < 2; ++pass) {
    const int tile = pass == 0 ? pair : 31 - pair;
    const int q0 = tile * 64 + w * 16;
    const int nkb = (tile >> 1) + 1;

    bf16x8 qf[2];
#pragma unroll
    for (int kk = 0; kk < 2; ++kk)
      qf[kk] = *(const bf16x8*)&Q[base + (size_t)(q0 + rr) * 64 + kk * 32 + kg * 8];

    f32x4 Oa[4] = {};
    float Mx[4], Ls[4];
#pragma unroll
    for (int r = 0; r < 4; ++r) { Mx[r] = -INFINITY; Ls[r] = 0.0f; }

    __syncthreads();                 // prior pass done reading LDS
    stage(0, 0);
    int cur = 0;

#pragma unroll 1
    for (int kb = 0; kb < nkb; ++kb) {
      __syncthreads();               // implicit vmcnt(0): buf[cur] ready
      if (kb + 1 < nkb) stage(cur ^ 1, kb + 1);   // overlap with compute

      // S = Q K^T   (16 rows x 128 cols)
      f32x4 S[8] = {};
#pragma unroll
      for (int f = 0; f < 8; ++f) {
#pragma unroll
        for (int kk = 0; kk < 2; ++kk) {
          bf16x8 kf = *(const bf16x8*)&Kt[cur][(f * 16 + rr) * 64 + (((kk * 4 + kg) ^ s7) * 8)];
          S[f] = mfma16(qf[kk], kf, S[f]);
        }
      }

      if (kb == nkb - 1) {           // diagonal block: causal mask
#pragma unroll
        for (int r = 0; r < 4; ++r) {
          const int qrow = q0 + kg * 4 + r;
#pragma unroll
          for (int f = 0; f < 8; ++f)
            S[f][r] = (kb * 128 + f * 16 + rr <= qrow) ? S[f][r] : -INFINITY;
        }
      }

      // defer-max: local maxima, rescale only if some row grew past THR=8
      float pmax[4];
#pragma unroll
      for (int r = 0; r < 4; ++r) {
        float a = fmaxf(fmaxf(S[0][r], S[1][r]), fmaxf(S[2][r], S[3][r]));
        float b = fmaxf(fmaxf(S[4][r], S[5][r]), fmaxf(S[6][r], S[7][r]));
        pmax[r] = fmaxf(a, b);
      }
      bool need = (pmax[0] > Mx[0] + 8.0f) | (pmax[1] > Mx[1] + 8.0f) |
                  (pmax[2] > Mx[2] + 8.0f) | (pmax[3] > Mx[3] + 8.0f);
      if (__any(need)) {             // rare path: full online-softmax update
#pragma unroll
        for (int r = 0; r < 4; ++r) {
          float mx = pmax[r];
#pragma unroll
          for (int d = 1; d < 16; d <<= 1) mx = fmaxf(mx, __shfl_xor(mx, d, 64));
          const float newM = fmaxf(Mx[r], mx);
          const float alpha = __expf(Mx[r] - newM);
          Ls[r] *= alpha;
#pragma unroll
          for (int df = 0; df < 4; ++df) Oa[df][r] *= alpha;
          Mx[r] = newM;
        }
      }

      // P = exp(S - Mx); accumulate per-lane row-sum; store P tile (swizzled)
#pragma unroll
      for (int r = 0; r < 4; ++r) {
        const int prow = kg * 4 + r;
        float rs = 0.0f;
#pragma unroll
        for (int f = 0; f < 8; ++f) {
          float p = __expf(S[f][r] - Mx[r]);
          rs += p;
          int cb = (f * 2 + (rr >> 3)) ^ (prow & 7);
          Pt[w][prow * 128 + cb * 8 + (rr & 7)] = __float2bfloat16(p);
        }
        Ls[r] += rs;
      }

      // O += P V   (wave-local P reads; no barrier needed)
#pragma unroll
      for (int kk2 = 0; kk2 < 4; ++kk2) {
        bf16x8 pf = *(const bf16x8*)&Pt[w][rr * 128 + (((kk2 * 4 + kg) ^ s7) * 8)];
#pragma unroll
        for (int df = 0; df < 4; ++df) {
          bf16x8 vf = *(const bf16x8*)&Vt[cur][(df * 16 + rr) * 128 + (((kk2 * 4 + kg) ^ s7) * 8)];
          Oa[df] = mfma16(pf, vf, Oa[df]);
        }
      }
      cur ^= 1;
    }

    // epilogue: reduce row-sums once, normalize, write O as [bv][s][h*64+d]
#pragma unroll
    for (int r = 0; r < 4; ++r) {
#pragma unroll
      for (int d = 1; d < 16; d <<= 1) Ls[r] += __shfl_xor(Ls[r], d, 64);
      const int qrow = q0 + kg * 4 + r;
      const float inv = 1.0f / Ls[r];
      size_t ob = ((size_t)bv * 2048 + qrow) * 512 + h * 64;
#pragma unroll
      for (int df = 0; df < 4; ++df)
        O[ob + df * 16 + rr] = __float2bfloat16(Oa[df][r] * inv);
    }
  }
}

// ---------------- launch ----------------

extern "C" void kernel_launch(void* const* d_in, const int* in_sizes, int n_in,
                              void* d_out, int out_size, void* d_ws, size_t ws_size,
                              hipStream_t stream)
{
  const float* x    = (const float*)d_in[1];
  const float* wqkv = (const float*)d_in[2];
  const float* bqkv = (const float*)d_in[3];
  const float* wo   = (const float*)d_in[4];
  const float* bo   = (const float*)d_in[5];
  float* out = (float*)d_out;

  char* p = (char*)d_ws;
  bf16* Xb   = (bf16*)p; p += (size_t)8192 * 512 * 2;
  bf16* Wqb  = (bf16*)p; p += (size_t)1536 * 512 * 2;
  bf16* Wob  = (bf16*)p; p += (size_t)512 * 512 * 2;
  bf16* QKVb = (bf16*)p; p += (size_t)8192 * 1536 * 2;
  bf16* Qr   = (bf16*)p; p += (size_t)32 * 2048 * 64 * 2;
  bf16* Kr   = (bf16*)p; p += (size_t)32 * 2048 * 64 * 2;
  bf16* VTr  = (bf16*)p; p += (size_t)32 * 2048 * 64 * 2;
  bf16* Ob   = (bf16*)p; p += (size_t)8192 * 512 * 2;
  float2* tab = (float2*)p; p += (size_t)2048 * 32 * 8;

  f2b4_kernel<<<4096, 256, 0, stream>>>((const float4*)x,    (ushort4*)Xb,  8192 * 512 / 4);
  f2b4_kernel<<<768,  256, 0, stream>>>((const float4*)wqkv, (ushort4*)Wqb, 1536 * 512 / 4);
  f2b4_kernel<<<256,  256, 0, stream>>>((const float4*)wo,   (ushort4*)Wob, 512 * 512 / 4);
  rope_table_kernel<<<256, 256, 0, stream>>>(tab);

  gemm_bt_kernel<bf16><<<dim3(64, 12), 256, 0, stream>>>(Xb, Wqb, bqkv, QKVb, 8192, 1536, 512);
  rope_reshape_kernel<<<8192, 256, 0, stream>>>(QKVb, tab, Qr, Kr);
  vtrans_kernel<<<dim3(32, 32), 256, 0, stream>>>(QKVb, VTr);
  attn_kernel<<<dim3(32, 16), 256, 0, stream>>>(Qr, Kr, VTr, Ob);
  gemm_bt_kernel<float><<<dim3(64, 4), 256, 0, stream>>>(Ob, Wob, bo, out, 8192, 512, 512);
}